// Round 1
// baseline (389.798 us; speedup 1.0000x reference)
//
#include <hip/hip_runtime.h>

#define HH   128
#define WW   128
#define CINN 64
#define COUTN 128
#define NBAT 8
#define NP   16          // 2 parts * 8 batch rows
#define VPB  32          // v positions per block
#define XSTRIDE 514      // padded per-c stride in xsh: 16*32 + 2 (odd word stride -> conflict-free transpose)
#define PLANE 8192       // CINN*COUTN

__device__ __forceinline__ unsigned short f2bf(float x) {
    unsigned u = __float_as_uint(x);
    unsigned r = (u + 0x7FFFu + ((u >> 16) & 1u)) >> 16;
    return (unsigned short)r;
}
__device__ __forceinline__ float bf2f(unsigned short h) {
    return __uint_as_float(((unsigned)h) << 16);
}

// Kernel A: per-(u,v) spectral mixing GEMM + per-channel sum/sumsq stats.
// Block = (u, v-quarter). Threads: t&31 -> o-quad, t>>5 -> local v.
__global__ __launch_bounds__(1024) void conv_stats(
    const float* __restrict__ xr, const float* __restrict__ xi,
    const float* __restrict__ filt, float* __restrict__ out,
    float* __restrict__ gstats)
{
    __shared__ unsigned short pq[5 * PLANE];        // 80 KB  (P0,P1,P2,Q1,Q2) bf16, [plane][c][o]
    __shared__ unsigned short xsh[CINN * XSTRIDE];  // 64.25 KB bf16, [c][np][v] padded
    __shared__ float statl[512];                    // 2 KB

    const int t = threadIdx.x;
    const int u = blockIdx.x >> 2;
    const int vbase = (blockIdx.x & 3) * VPB;

    // ---- P/Q planes (depend on u only): P_b = f0b + cu1*f1b + cu2*f2b ; Q_b = su1*f1b + su2*f2b
    const float au = 6.28318530717958647692f * (float)u / 128.0f;
    float su1, cu1, su2, cu2;
    sincosf(au, &su1, &cu1);
    sincosf(2.0f * au, &su2, &cu2);

    for (int i = t; i < PLANE; i += 1024) {           // i = c*128 + o
        #pragma unroll
        for (int b = 0; b < 3; ++b) {
            float f0 = filt[(0 * 3 + b) * PLANE + i];
            float f1 = filt[(1 * 3 + b) * PLANE + i];
            float f2 = filt[(2 * 3 + b) * PLANE + i];
            float P = f0 + cu1 * f1 + cu2 * f2;
            pq[b * PLANE + i] = f2bf(P);
            if (b > 0) {
                float Q = su1 * f1 + su2 * f2;
                pq[(b + 2) * PLANE + i] = f2bf(Q);
            }
        }
    }

    // ---- stage x' tiles: xr'=r+i (part0), xi'=i-r (part1), layout [c][np][v]
    for (int p = t; p < VPB * NBAT * CINN; p += 1024) {   // 16384 pairs
        int c  = p & 63;
        int n  = (p >> 6) & 7;
        int vl = p >> 9;
        size_t gi = ((size_t)(n * HH + u) * WW + (size_t)(vbase + vl)) * CINN + c;
        float r  = xr[gi];
        float im = xi[gi];
        xsh[c * XSTRIDE + n * VPB + vl]       = f2bf(r + im);
        xsh[c * XSTRIDE + (8 + n) * VPB + vl] = f2bf(im - r);
    }
    __syncthreads();

    // ---- per-thread GEMM: 16 np rows x 4 o cols for one v
    const int o4 = (t & 31) * 4;
    const int vl = t >> 5;
    const int v  = vbase + vl;

    const float av = 6.28318530717958647692f * (float)v / 128.0f;
    float sv1, cv1, sv2, cv2;
    sincosf(av, &sv1, &cv1);
    sincosf(2.0f * av, &sv2, &cv2);

    float acc[NP][4];
    #pragma unroll
    for (int np = 0; np < NP; ++np)
        #pragma unroll
        for (int j = 0; j < 4; ++j) acc[np][j] = 0.0f;

    #pragma unroll 2
    for (int c = 0; c < CINN; ++c) {
        const unsigned short* pp = &pq[c * COUTN + o4];
        ushort4 P0 = *(const ushort4*)(pp);
        ushort4 P1 = *(const ushort4*)(pp + PLANE);
        ushort4 P2 = *(const ushort4*)(pp + 2 * PLANE);
        ushort4 Q1 = *(const ushort4*)(pp + 3 * PLANE);
        ushort4 Q2 = *(const ushort4*)(pp + 4 * PLANE);
        float kr0 = bf2f(P0.x) + cv1 * bf2f(P1.x) + cv2 * bf2f(P2.x) - sv1 * bf2f(Q1.x) - sv2 * bf2f(Q2.x);
        float kr1 = bf2f(P0.y) + cv1 * bf2f(P1.y) + cv2 * bf2f(P2.y) - sv1 * bf2f(Q1.y) - sv2 * bf2f(Q2.y);
        float kr2 = bf2f(P0.z) + cv1 * bf2f(P1.z) + cv2 * bf2f(P2.z) - sv1 * bf2f(Q1.z) - sv2 * bf2f(Q2.z);
        float kr3 = bf2f(P0.w) + cv1 * bf2f(P1.w) + cv2 * bf2f(P2.w) - sv1 * bf2f(Q1.w) - sv2 * bf2f(Q2.w);
        const unsigned short* xp = &xsh[c * XSTRIDE + vl];
        #pragma unroll
        for (int np = 0; np < NP; ++np) {
            float xv = bf2f(xp[np * VPB]);
            acc[np][0] = fmaf(xv, kr0, acc[np][0]);
            acc[np][1] = fmaf(xv, kr1, acc[np][1]);
            acc[np][2] = fmaf(xv, kr2, acc[np][2]);
            acc[np][3] = fmaf(xv, kr3, acc[np][3]);
        }
    }

    // ---- store raw conv + per-thread stats
    float ssum[2][4] = {{0,0,0,0},{0,0,0,0}};
    float ssq [2][4] = {{0,0,0,0},{0,0,0,0}};
    const size_t obase = ((size_t)u * WW + (size_t)v) * COUTN + o4;
    #pragma unroll
    for (int np = 0; np < NP; ++np) {
        const int n = np & 7, part = np >> 3;
        float4 y;
        y.x = acc[np][0]; y.y = acc[np][1]; y.z = acc[np][2]; y.w = acc[np][3];
        size_t oi = (size_t)part * 16777216 + (size_t)n * (HH * WW * COUTN) + obase;
        *(float4*)(out + oi) = y;
        ssum[part][0] += y.x; ssq[part][0] += y.x * y.x;
        ssum[part][1] += y.y; ssq[part][1] += y.y * y.y;
        ssum[part][2] += y.z; ssq[part][2] += y.z * y.z;
        ssum[part][3] += y.w; ssq[part][3] += y.w * y.w;
    }

    // ---- block-level stats reduction -> global atomics
    if (t < 512) statl[t] = 0.0f;
    __syncthreads();
    #pragma unroll
    for (int part = 0; part < 2; ++part)
        #pragma unroll
        for (int j = 0; j < 4; ++j) {
            atomicAdd(&statl[part * 128 + o4 + j], ssum[part][j]);
            atomicAdd(&statl[256 + part * 128 + o4 + j], ssq[part][j]);
        }
    __syncthreads();
    if (t < 512) atomicAdd(&gstats[t], statl[t]);
}

// Kernel B0: stats -> per-channel scale/shift
__global__ void bn_prep(const float* __restrict__ gstats,
                        const float* __restrict__ gr, const float* __restrict__ br,
                        const float* __restrict__ gi, const float* __restrict__ bi,
                        float* __restrict__ sc_sh)
{
    int t = threadIdx.x;
    if (t < 256) {
        int part = t >> 7, o = t & 127;
        const float inv = 1.0f / 131072.0f;
        float mean = gstats[t] * inv;
        float var  = gstats[256 + t] * inv - mean * mean;
        float g = part ? gi[o] : gr[o];
        float b = part ? bi[o] : br[o];
        float s = g * rsqrtf(var + 1e-3f);
        sc_sh[t]       = s;
        sc_sh[256 + t] = b - mean * s;
    }
}

// Kernel B1: in-place BN + LeakyReLU(0.2), float4 per thread
__global__ __launch_bounds__(256) void bn_apply(float* __restrict__ out,
                                                const float* __restrict__ sc_sh)
{
    size_t e = ((size_t)blockIdx.x * 256 + (size_t)threadIdx.x) * 4;
    int part = (int)(e >> 24);
    int o = (int)(e & 127);
    const float4 sc = *(const float4*)(sc_sh + part * 128 + o);
    const float4 sh = *(const float4*)(sc_sh + 256 + part * 128 + o);
    float4 x = *(float4*)(out + e);
    float y0 = fmaf(x.x, sc.x, sh.x);
    float y1 = fmaf(x.y, sc.y, sh.y);
    float y2 = fmaf(x.z, sc.z, sh.z);
    float y3 = fmaf(x.w, sc.w, sh.w);
    x.x = y0 >= 0.0f ? y0 : 0.2f * y0;
    x.y = y1 >= 0.0f ? y1 : 0.2f * y1;
    x.z = y2 >= 0.0f ? y2 : 0.2f * y2;
    x.w = y3 >= 0.0f ? y3 : 0.2f * y3;
    *(float4*)(out + e) = x;
}

extern "C" void kernel_launch(void* const* d_in, const int* in_sizes, int n_in,
                              void* d_out, int out_size, void* d_ws, size_t ws_size,
                              hipStream_t stream)
{
    const float* xr   = (const float*)d_in[0];
    const float* xi   = (const float*)d_in[1];
    const float* filt = (const float*)d_in[2];
    const float* gr   = (const float*)d_in[3];
    const float* br   = (const float*)d_in[4];
    const float* gi   = (const float*)d_in[5];
    const float* bi   = (const float*)d_in[6];
    float* out = (float*)d_out;
    float* ws  = (float*)d_ws;

    hipMemsetAsync(ws, 0, 512 * sizeof(float), stream);
    conv_stats<<<dim3(512), dim3(1024), 0, stream>>>(xr, xi, filt, out, ws);
    bn_prep<<<dim3(1), dim3(256), 0, stream>>>(ws, gr, br, gi, bi, ws + 512);
    bn_apply<<<dim3(32768), dim3(256), 0, stream>>>(out, ws + 512);
}

// Round 3
// 301.201 us; speedup vs baseline: 1.2941x; 1.2941x over previous
//
#include <hip/hip_runtime.h>
#include <hip/hip_bf16.h>

// Layout/design notes:
//  - kr[u,v,c,o] = P0 + cv1*P1 + cv2*P2 - sv1*Q1 - sv2*Q2 where planes P/Q depend on u only.
//  - Block = (u, v-sixteenth): stages 5 planes (bf16, [plane][o][c], stride 72) + x' tiles
//    (bf16, [v][np][c], stride 72; np0-7 = r+i, np8-15 = i-r).
//  - Wave = (vgroup of 4 v, nt-half of 4 o-tiles). Per (nt,ks): 5 ds_read_b128 plane frags,
//    unpack once, synthesize bf16 B-frag per v (4 FMA/value), mfma_f32_16x16x32_bf16.
//    A-frag = one ds_read_b128 from xsh (layout matches MFMA A register order exactly).
//  - C layout: col(o)=lane&15, row(np)=(lane>>4)*4+reg  [guide §3, m89/m91 verified].
//  - Stride 72 shorts = 144 B: 16B-aligned b128 reads, <=2-way bank aliasing on reads.

typedef __bf16 bf16x8 __attribute__((ext_vector_type(8)));
typedef float f32x4 __attribute__((ext_vector_type(4)));

#define PQ_STRIDE   72          // shorts per o-row
#define PQ_PLANE    (128 * PQ_STRIDE)
#define XS_STRIDE   72
#define XS_NP       (16 * XS_STRIDE)

__device__ __forceinline__ unsigned short f2bf(float x) {
    unsigned u = __float_as_uint(x);
    return (unsigned short)((u + 0x7FFFu + ((u >> 16) & 1u)) >> 16);
}
__device__ __forceinline__ unsigned pack2(float a, float b) {
    __hip_bfloat162 h = __float22bfloat162_rn(make_float2(a, b));
    return *reinterpret_cast<unsigned*>(&h);
}
__device__ __forceinline__ void unpack8(uint4 u, float* f) {
    f[0] = __uint_as_float(u.x << 16); f[1] = __uint_as_float(u.x & 0xffff0000u);
    f[2] = __uint_as_float(u.y << 16); f[3] = __uint_as_float(u.y & 0xffff0000u);
    f[4] = __uint_as_float(u.z << 16); f[5] = __uint_as_float(u.z & 0xffff0000u);
    f[6] = __uint_as_float(u.w << 16); f[7] = __uint_as_float(u.w & 0xffff0000u);
}

__global__ __launch_bounds__(512, 2) void conv_stats(
    const float* __restrict__ xr, const float* __restrict__ xi,
    const float* __restrict__ filt, float* __restrict__ out,
    float* __restrict__ gstats)
{
    __shared__ __align__(16) unsigned short pqT[5 * PQ_PLANE]; // 92160 B
    __shared__ __align__(16) unsigned short xsh[16 * XS_NP];   // 36864 B
    __shared__ float statl[512];                               // 2048 B

    const int t = threadIdx.x;
    const int u = blockIdx.x >> 3;
    const int vbase = (blockIdx.x & 7) * 16;

    // ---- stage P/Q planes (u-dependent): pairs of c packed into one b32 write
    const float au = 6.28318530717958647692f * (float)u / 128.0f;
    float su1, cu1, su2, cu2;
    __sincosf(au, &su1, &cu1);
    __sincosf(2.0f * au, &su2, &cu2);
    unsigned* pq32 = (unsigned*)pqT;

    #pragma unroll
    for (int k = 0; k < 8; ++k) {               // 4096 (o, c-pair) items
        int i = t + k * 512;
        int o = i & 127;
        int cp = i >> 7;                        // 0..31 -> c = 2cp, 2cp+1
        int g0 = (2 * cp) * 128 + o;
        int g1 = g0 + 128;
        unsigned widx = o * 36 + cp;            // uint index within a plane (4608/plane)
        #pragma unroll
        for (int b = 0; b < 3; ++b) {
            float f0a = filt[b * 8192 + g0],        f0b = filt[b * 8192 + g1];
            float f1a = filt[(3 + b) * 8192 + g0],  f1b = filt[(3 + b) * 8192 + g1];
            float f2a = filt[(6 + b) * 8192 + g0],  f2b = filt[(6 + b) * 8192 + g1];
            float Pa = f0a + cu1 * f1a + cu2 * f2a;
            float Pb = f0b + cu1 * f1b + cu2 * f2b;
            pq32[b * 4608 + widx] = pack2(Pa, Pb);
            if (b > 0) {
                float Qa = su1 * f1a + su2 * f2a;
                float Qb = su1 * f1b + su2 * f2b;
                pq32[(b + 2) * 4608 + widx] = pack2(Qa, Qb);
            }
        }
    }

    // ---- stage x' tiles bf16 [v][np][c] (np = n for r+i, 8+n for i-r)
    #pragma unroll
    for (int k = 0; k < 16; ++k) {              // 8192 (v,n,c) items
        int p = t + k * 512;
        int c = p & 63;
        int v = (p >> 6) & 15;
        int n = p >> 10;
        size_t gi = ((size_t)(n * 128 + u) * 128 + (size_t)(vbase + v)) * 64 + c;
        float r = xr[gi], im = xi[gi];
        xsh[v * XS_NP + n * XS_STRIDE + c]       = f2bf(r + im);
        xsh[v * XS_NP + (8 + n) * XS_STRIDE + c] = f2bf(im - r);
    }
    __syncthreads();

    // ---- wave assignment
    const int wave = t >> 6;
    const int lane = t & 63;
    const int vg   = wave >> 1;      // 4 v's: vbase + vg*4 + 0..3
    const int nth  = wave & 1;       // o-tiles nth*4 .. nth*4+3
    const int ln15 = lane & 15;
    const int q    = lane >> 4;      // 0..3

    // per-v trig coefficients
    float cv1[4], cv2[4], nsv1[4], nsv2[4];
    #pragma unroll
    for (int vj = 0; vj < 4; ++vj) {
        float av = 6.28318530717958647692f * (float)(vbase + vg * 4 + vj) / 128.0f;
        float s1, c1, s2, c2;
        __sincosf(av, &s1, &c1);
        __sincosf(2.0f * av, &s2, &c2);
        cv1[vj] = c1; cv2[vj] = c2; nsv1[vj] = -s1; nsv2[vj] = -s2;
    }

    // A-fragments: one b128 each, register layout == MFMA A layout
    bf16x8 af[4][2];
    #pragma unroll
    for (int vj = 0; vj < 4; ++vj) {
        const unsigned short* xrow = &xsh[(vg * 4 + vj) * XS_NP + ln15 * XS_STRIDE];
        af[vj][0] = __builtin_bit_cast(bf16x8, *(const uint4*)(xrow + q * 8));
        af[vj][1] = __builtin_bit_cast(bf16x8, *(const uint4*)(xrow + 32 + q * 8));
    }

    f32x4 acc[4][4];
    #pragma unroll
    for (int vj = 0; vj < 4; ++vj)
        #pragma unroll
        for (int ntl = 0; ntl < 4; ++ntl)
            acc[vj][ntl] = (f32x4){0.f, 0.f, 0.f, 0.f};

    // ---- main loop: plane frags read+unpacked once, reused across 4 v
    #pragma unroll
    for (int ntl = 0; ntl < 4; ++ntl) {
        const int o = (nth * 4 + ntl) * 16 + ln15;
        const unsigned short* prow = &pqT[o * PQ_STRIDE];
        #pragma unroll
        for (int ks = 0; ks < 2; ++ks) {
            const int coff = ks * 32 + q * 8;
            float P0[8], P1[8], P2[8], Q1[8], Q2[8];
            unpack8(*(const uint4*)(prow + 0 * PQ_PLANE + coff), P0);
            unpack8(*(const uint4*)(prow + 1 * PQ_PLANE + coff), P1);
            unpack8(*(const uint4*)(prow + 2 * PQ_PLANE + coff), P2);
            unpack8(*(const uint4*)(prow + 3 * PQ_PLANE + coff), Q1);
            unpack8(*(const uint4*)(prow + 4 * PQ_PLANE + coff), Q2);
            #pragma unroll
            for (int vj = 0; vj < 4; ++vj) {
                float kr[8];
                #pragma unroll
                for (int j = 0; j < 8; ++j) {
                    float tv = fmaf(cv1[vj], P1[j], P0[j]);
                    tv = fmaf(cv2[vj], P2[j], tv);
                    tv = fmaf(nsv1[vj], Q1[j], tv);
                    kr[j] = fmaf(nsv2[vj], Q2[j], tv);
                }
                uint4 B;
                B.x = pack2(kr[0], kr[1]); B.y = pack2(kr[2], kr[3]);
                B.z = pack2(kr[4], kr[5]); B.w = pack2(kr[6], kr[7]);
                acc[vj][ntl] = __builtin_amdgcn_mfma_f32_16x16x32_bf16(
                    af[vj][ks], __builtin_bit_cast(bf16x8, B), acc[vj][ntl], 0, 0, 0);
            }
        }
    }

    // ---- epilogue: store + stats. C: col(o)=ln15, row(np)=q*4+reg
    float ssum[4] = {0, 0, 0, 0}, ssq[4] = {0, 0, 0, 0};
    const int part = q >> 1;
    const int nbase = (q & 1) * 4;
    #pragma unroll
    for (int vj = 0; vj < 4; ++vj) {
        const int v = vbase + vg * 4 + vj;
        const size_t pos = ((size_t)(u * 128 + v)) * 128;
        #pragma unroll
        for (int ntl = 0; ntl < 4; ++ntl) {
            const int o = (nth * 4 + ntl) * 16 + ln15;
            size_t base = (size_t)part * 16777216 + (size_t)nbase * 2097152 + pos + o;
            #pragma unroll
            for (int r = 0; r < 4; ++r) {
                float y = acc[vj][ntl][r];
                __builtin_nontemporal_store(y, out + base + (size_t)r * 2097152);
                ssum[ntl] += y;
                ssq[ntl] = fmaf(y, y, ssq[ntl]);
            }
        }
    }

    statl[t] = 0.f;
    __syncthreads();
    #pragma unroll
    for (int ntl = 0; ntl < 4; ++ntl) {
        int ch = part * 128 + (nth * 4 + ntl) * 16 + ln15;
        atomicAdd(&statl[ch], ssum[ntl]);
        atomicAdd(&statl[256 + ch], ssq[ntl]);
    }
    __syncthreads();
    atomicAdd(&gstats[t], statl[t]);
}

// stats -> per-channel scale/shift
__global__ void bn_prep(const float* __restrict__ gstats,
                        const float* __restrict__ gr, const float* __restrict__ br,
                        const float* __restrict__ gi, const float* __restrict__ bi,
                        float* __restrict__ sc_sh)
{
    int t = threadIdx.x;
    if (t < 256) {
        int part = t >> 7, o = t & 127;
        const float inv = 1.0f / 131072.0f;
        float mean = gstats[t] * inv;
        float var  = gstats[256 + t] * inv - mean * mean;
        float g = part ? gi[o] : gr[o];
        float b = part ? bi[o] : br[o];
        float s = g * rsqrtf(var + 1e-3f);
        sc_sh[t]       = s;
        sc_sh[256 + t] = b - mean * s;
    }
}

// in-place BN + LeakyReLU(0.2): grid-stride, nontemporal f32x4 (ext-vector, not HIP float4)
__global__ __launch_bounds__(256) void bn_apply(float* __restrict__ out,
                                                const float* __restrict__ sc_sh)
{
    size_t base = (size_t)blockIdx.x * 256 + threadIdx.x;
    #pragma unroll
    for (int it = 0; it < 4; ++it, base += (size_t)8192 * 256) {
        size_t e = base * 4;
        int part = (int)(e >> 24);
        int o = (int)(e & 127);
        const f32x4 sc = *(const f32x4*)(sc_sh + part * 128 + o);
        const f32x4 sh = *(const f32x4*)(sc_sh + 256 + part * 128 + o);
        f32x4 x = __builtin_nontemporal_load((const f32x4*)(out + e));
        f32x4 y;
        y[0] = fmaf(x[0], sc[0], sh[0]);
        y[1] = fmaf(x[1], sc[1], sh[1]);
        y[2] = fmaf(x[2], sc[2], sh[2]);
        y[3] = fmaf(x[3], sc[3], sh[3]);
        x[0] = y[0] >= 0.0f ? y[0] : 0.2f * y[0];
        x[1] = y[1] >= 0.0f ? y[1] : 0.2f * y[1];
        x[2] = y[2] >= 0.0f ? y[2] : 0.2f * y[2];
        x[3] = y[3] >= 0.0f ? y[3] : 0.2f * y[3];
        __builtin_nontemporal_store(x, (f32x4*)(out + e));
    }
}

extern "C" void kernel_launch(void* const* d_in, const int* in_sizes, int n_in,
                              void* d_out, int out_size, void* d_ws, size_t ws_size,
                              hipStream_t stream)
{
    const float* xr   = (const float*)d_in[0];
    const float* xi   = (const float*)d_in[1];
    const float* filt = (const float*)d_in[2];
    const float* gr   = (const float*)d_in[3];
    const float* br   = (const float*)d_in[4];
    const float* gi   = (const float*)d_in[5];
    const float* bi   = (const float*)d_in[6];
    float* out = (float*)d_out;
    float* ws  = (float*)d_ws;

    (void)hipMemsetAsync(ws, 0, 512 * sizeof(float), stream);
    conv_stats<<<dim3(1024), dim3(512), 0, stream>>>(xr, xi, filt, out, ws);
    bn_prep<<<dim3(1), dim3(256), 0, stream>>>(ws, gr, br, gi, bi, ws + 512);
    bn_apply<<<dim3(8192), dim3(256), 0, stream>>>(out, ws + 512);
}